// Round 6
// baseline (139.129 us; speedup 1.0000x reference)
//
#include <hip/hip_runtime.h>

#define NB    256
#define UNITS 1024
#define EDIM  1024
#define MEM   128
#define LDA   2048   // inputs row stride (EDIM + UNITS)

// d_out layout (floats): output[256*1024] | new_M_key[256*128*1024] | new_M_value[256*128*1024]
#define KEY_OFF ((size_t)NB * UNITS)
#define VAL_OFF (KEY_OFF + (size_t)NB * MEM * UNITS)

#define NGEMM 128                 // GEMM blocks (first in grid)
#define GROUP_F 4224              // GEMM: floats per split-K group region (As 32x68 + Bs 32x64)
#define SMEM_FLOATS (4 * GROUP_F) // 67584 B; fused path uses 5376 floats of it

typedef float nfloat4 __attribute__((ext_vector_type(4)));

__device__ __forceinline__ void nt_store4(float* p, float4 v) {
    nfloat4 nv = {v.x, v.y, v.z, v.w};
    __builtin_nontemporal_store(nv, (nfloat4*)p);
}
__device__ __forceinline__ float4 nt_load4(const float* p) {
    nfloat4 v = __builtin_nontemporal_load((const nfloat4*)p);
    return make_float4(v.x, v.y, v.z, v.w);
}

// Blocks 0..127: two 256x1024x1024 fp32 GEMMs (row 127 of new_M_*), LDS-staged,
//   in-block split-K=4 (R4 structure, proven).
// Blocks 128..383: fused path, restructured for max memory-level parallelism:
//   Phase 1: dependency-free stream over K AND V rows — copy both (nt stores),
//            per-lane dot partials into acc[8]; K via nt loads (read-once,
//            don't pollute L3), V via normal loads (L3-resident for Phase 2).
//   (shuffle reduces AFTER the loop) -> softmax -> Phase 2: re-read V from L3,
//   weighted sum (R4 phase-C structure minus the copy).
__global__ __launch_bounds__(1024, 8) void k_all(
    const float* __restrict__ inputs, const float* __restrict__ M_key,
    const float* __restrict__ M_value, const float* __restrict__ W_key,
    const float* __restrict__ W_value, float* __restrict__ out)
{
    __shared__ __align__(16) float smem[SMEM_FLOATS];
    const int tid = threadIdx.x;

    if (blockIdx.x >= NGEMM) {
        // ========================= fused path =========================
        float* h_s  = smem;                          // 1024
        float* lg_s = smem + 1024;                   // 128
        float* at_s = smem + 1152;                   // 128
        float (*red_s)[1024] = (float (*)[1024])(smem + 1280); // 4 x 1024

        const int b    = blockIdx.x - NGEMM;
        const int wave = tid >> 6;
        const int lane = tid & 63;

        h_s[tid] = inputs[(size_t)b * LDA + EDIM + tid];
        __syncthreads();                                       // bar 1

        const float4 h0 = *(const float4*)(&h_s[lane * 4]);
        const float4 h1 = *(const float4*)(&h_s[lane * 4 + 256]);
        const float4 h2 = *(const float4*)(&h_s[lane * 4 + 512]);
        const float4 h3 = *(const float4*)(&h_s[lane * 4 + 768]);

        const size_t mb = (size_t)b * (MEM * UNITS);
        const float* kb = M_key   + mb + lane * 4;
        const float* vb = M_value + mb + lane * 4;
        float*       ko = out + KEY_OFF + mb + lane * 4;
        float*       vo = out + VAL_OFF + mb + lane * 4;

        // ---- Phase 1: pure stream: copy K & V, per-lane dot partials ----
        float accr[8];
        #pragma unroll
        for (int r = 0; r < 8; ++r) {
            const int m = wave * 8 + r;
            const float* kr = kb + (size_t)m * UNITS;
            const float* vr = vb + (size_t)m * UNITS;
            float* kd = ko + (size_t)(m - 1) * UNITS;
            float* vd = vo + (size_t)(m - 1) * UNITS;

            float4 k0 = nt_load4(kr);
            float4 k1 = nt_load4(kr + 256);
            float4 k2 = nt_load4(kr + 512);
            float4 k3 = nt_load4(kr + 768);
            accr[r] = k0.x*h0.x + k0.y*h0.y + k0.z*h0.z + k0.w*h0.w
                    + k1.x*h1.x + k1.y*h1.y + k1.z*h1.z + k1.w*h1.w
                    + k2.x*h2.x + k2.y*h2.y + k2.z*h2.z + k2.w*h2.w
                    + k3.x*h3.x + k3.y*h3.y + k3.z*h3.z + k3.w*h3.w;
            if (m > 0) {
                nt_store4(kd,       k0);
                nt_store4(kd + 256, k1);
                nt_store4(kd + 512, k2);
                nt_store4(kd + 768, k3);
            }

            float4 v0 = *(const float4*)(vr);
            float4 v1 = *(const float4*)(vr + 256);
            float4 v2 = *(const float4*)(vr + 512);
            float4 v3 = *(const float4*)(vr + 768);
            if (m > 0) {
                nt_store4(vd,       v0);
                nt_store4(vd + 256, v1);
                nt_store4(vd + 512, v2);
                nt_store4(vd + 768, v3);
            }
        }

        // cross-lane reduces, off the stream path
        #pragma unroll
        for (int r = 0; r < 8; ++r) {
            float a = accr[r];
            #pragma unroll
            for (int off = 32; off > 0; off >>= 1)
                a += __shfl_xor(a, off);
            if (lane == 0) lg_s[wave * 8 + r] = a;
        }
        __syncthreads();                                       // bar 2

        // ---- softmax over 128 logits (wave 0) ----
        if (wave == 0) {
            float l0 = lg_s[lane], l1 = lg_s[lane + 64];
            float mx = fmaxf(l0, l1);
            #pragma unroll
            for (int off = 32; off > 0; off >>= 1)
                mx = fmaxf(mx, __shfl_xor(mx, off));
            float e0 = __expf(l0 - mx), e1 = __expf(l1 - mx);
            float s = e0 + e1;
            #pragma unroll
            for (int off = 32; off > 0; off >>= 1)
                s += __shfl_xor(s, off);
            float inv = 1.0f / s;
            at_s[lane]      = e0 * inv;
            at_s[lane + 64] = e1 * inv;
        }
        __syncthreads();                                       // bar 3

        // ---- Phase 2: weighted sum, V re-read from L3 ----
        {
            const int rc  = wave >> 2;                 // 0..3 -> 32 rows each
            const int col = (wave & 3) * 256 + lane * 4;
            const float* vbase = M_value + mb + col;

            float4 acc = {0.f, 0.f, 0.f, 0.f};
            #pragma unroll 4
            for (int r = 0; r < 32; ++r) {
                const int m = rc * 32 + r;
                float4 v = *(const float4*)(vbase + (size_t)m * UNITS);
                const float w = at_s[m];
                acc.x = fmaf(w, v.x, acc.x); acc.y = fmaf(w, v.y, acc.y);
                acc.z = fmaf(w, v.z, acc.z); acc.w = fmaf(w, v.w, acc.w);
            }
            *(float4*)(&red_s[rc][col]) = acc;
        }
        __syncthreads();                                       // bar 4

        if (wave < 4) {
            const int col = wave * 256 + lane * 4;
            float4 a0 = *(const float4*)(&red_s[0][col]);
            float4 a1 = *(const float4*)(&red_s[1][col]);
            float4 a2 = *(const float4*)(&red_s[2][col]);
            float4 a3 = *(const float4*)(&red_s[3][col]);
            float4 s = {a0.x + a1.x + a2.x + a3.x,
                        a0.y + a1.y + a2.y + a3.y,
                        a0.z + a1.z + a2.z + a3.z,
                        a0.w + a1.w + a2.w + a3.w};
            *(float4*)(out + (size_t)b * UNITS + col) = s;
        }
    } else {
        // ========================= GEMM path (R4 structure) =========================
        const int t  = blockIdx.x;            // 0..127
        const int w  = t >> 6;                // which W matrix
        const int r  = t & 63;
        const int mt = r >> 4;                // 0..3  (64 rows)
        const int nt = r & 15;                // 0..15 (64 cols)
        const int kc   = tid >> 8;            // 0..3 (split-K group)
        const int gtid = tid & 255;
        const int ty = gtid >> 4, tx = gtid & 15;

        float* region = smem + kc * GROUP_F;
        float (*As)[68] = (float (*)[68])region;            // [k][m]
        float (*Bs)[64] = (float (*)[64])(region + 2176);   // [k][n]
        const float* Wm = w ? W_value : W_key;

        float acc[4][4] = {};
        const int k0 = kc * 256;

        for (int kt = k0; kt < k0 + 256; kt += 32) {
            #pragma unroll
            for (int q = 0; q < 2; ++q) {
                const int f  = gtid * 2 + q;          // 0..511
                const int ar = f >> 3;                // 0..63
                const int ac = (f & 7) << 2;          // 0..28
                float4 a = *(const float4*)(inputs + (size_t)(mt * 64 + ar) * LDA + kt + ac);
                As[ac + 0][ar] = a.x;
                As[ac + 1][ar] = a.y;
                As[ac + 2][ar] = a.z;
                As[ac + 3][ar] = a.w;
            }
            #pragma unroll
            for (int q = 0; q < 2; ++q) {
                const int f  = gtid * 2 + q;
                const int br = f >> 4;                // 0..31
                const int bc = (f & 15) << 2;         // 0..60
                *(float4*)(&Bs[br][bc]) =
                    *(const float4*)(Wm + (size_t)(kt + br) * UNITS + nt * 64 + bc);
            }
            __syncthreads();

            #pragma unroll
            for (int kk = 0; kk < 32; ++kk) {
                const float4 av = *(const float4*)(&As[kk][ty * 4]);
                const float4 bv = *(const float4*)(&Bs[kk][tx * 4]);
                acc[0][0] += av.x * bv.x; acc[0][1] += av.x * bv.y; acc[0][2] += av.x * bv.z; acc[0][3] += av.x * bv.w;
                acc[1][0] += av.y * bv.x; acc[1][1] += av.y * bv.y; acc[1][2] += av.y * bv.z; acc[1][3] += av.y * bv.w;
                acc[2][0] += av.z * bv.x; acc[2][1] += av.z * bv.y; acc[2][2] += av.z * bv.z; acc[2][3] += av.z * bv.w;
                acc[3][0] += av.w * bv.x; acc[3][1] += av.w * bv.y; acc[3][2] += av.w * bv.z; acc[3][3] += av.w * bv.w;
            }
            __syncthreads();
        }

        // each group writes its 64x64 partial over its own As/Bs region
        #pragma unroll
        for (int i = 0; i < 4; ++i) {
            float4 v = {acc[i][0], acc[i][1], acc[i][2], acc[i][3]};
            *(float4*)(region + (ty * 4 + i) * 64 + tx * 4) = v;
        }
        __syncthreads();

        // block-wide reduce of the 4 partials -> row 127 of new_M_{key,value}
        {
            const int e   = tid * 4;                  // 0..4092
            const int row = e >> 6;                   // 0..63
            const int col = e & 63;
            float4 p0 = *(const float4*)(smem + 0 * GROUP_F + e);
            float4 p1 = *(const float4*)(smem + 1 * GROUP_F + e);
            float4 p2 = *(const float4*)(smem + 2 * GROUP_F + e);
            float4 p3 = *(const float4*)(smem + 3 * GROUP_F + e);
            float4 s = {p0.x + p1.x + p2.x + p3.x,
                        p0.y + p1.y + p2.y + p3.y,
                        p0.z + p1.z + p2.z + p3.z,
                        p0.w + p1.w + p2.w + p3.w};
            *(float4*)(out + (w ? VAL_OFF : KEY_OFF)
                       + (size_t)(mt * 64 + row) * (MEM * UNITS)
                       + (size_t)(MEM - 1) * UNITS + nt * 64 + col) = s;
        }
    }
}

extern "C" void kernel_launch(void* const* d_in, const int* in_sizes, int n_in,
                              void* d_out, int out_size, void* d_ws, size_t ws_size,
                              hipStream_t stream)
{
    const float* inputs  = (const float*)d_in[0];
    const float* M_key   = (const float*)d_in[1];
    const float* M_value = (const float*)d_in[2];
    const float* W_key   = (const float*)d_in[3];
    const float* W_value = (const float*)d_in[4];
    float* out = (float*)d_out;

    hipLaunchKernelGGL(k_all, dim3(NGEMM + NB), dim3(1024), 0, stream,
                       inputs, M_key, M_value, W_key, W_value, out);
}